// Round 1
// baseline (959.540 us; speedup 1.0000x reference)
//
#include <hip/hip_runtime.h>
#include <stdint.h>

typedef unsigned short ushort_t;
typedef short s8v __attribute__((ext_vector_type(8)));
typedef float f4v __attribute__((ext_vector_type(4)));

#define NW 200000
#define NT 100000
#define EE 500000
#define NSEG (NT + NW + NW)   // concatenated dst slots: [tok(e_wt) | wal(e_tw) | wal(e_ww)]

__device__ __forceinline__ float b2f(unsigned short u){
  union { unsigned int i; float f; } v; v.i = ((unsigned int)u) << 16; return v.f;
}
__device__ __forceinline__ unsigned short f2b(float f){
  unsigned int x = __float_as_uint(f);
  unsigned int r = x + 0x7fffu + ((x >> 16) & 1u);   // RNE
  return (unsigned short)(r >> 16);
}
__device__ __forceinline__ float ldf(const void* p, long idx, int fm){
  return fm ? ((const float*)p)[idx] : b2f(((const ushort_t*)p)[idx]);
}

// ---------------- runtime dtype probes ----------------
// mode[0]: 1 = edges are int64, 0 = int32 ; mode[1]: 1 = floats are fp32, 0 = bf16
__global__ void detect_kern(const int* ewt, const int* etw, const int* eww,
                            const unsigned* xw_words, int* mode){
  if (threadIdx.x == 0 && blockIdx.x == 0){
    unsigned o = 0;
    for (int i = 0; i < 64; ++i)
      o |= (unsigned)ewt[2 * i + 1] | (unsigned)etw[2 * i + 1] | (unsigned)eww[2 * i + 1];
    mode[0] = (o == 0) ? 1 : 0;
    int viol = 0;
    for (int i = 0; i < 256; ++i){
      unsigned s = xw_words[i] & 0xffffu;
      unsigned e = (s >> 7) & 0xffu;
      if (!(s == 0u || s == 0x8000u || (e >= 90u && e <= 140u))) viol++;
    }
    mode[1] = (viol > 8) ? 1 : 0;
  }
}

// ------ batched weight transpose+convert: dst[n*K+k] = bf16(src[ebase + k*N + n]) ------
struct TDesc { const void* src; ushort_t* dst; long ebase; int K; int N; };
struct TDesc8 { TDesc d[8]; };
__global__ void transpose8(TDesc8 td, const int* mode){
  int fm = mode[1];
  int mi = blockIdx.x >> 6;
  TDesc t = td.d[mi];
  int e = ((blockIdx.x & 63) << 8) + threadIdx.x;
  if (e < t.K * t.N){
    int k = e / t.N, n = e - k * t.N;
    t.dst[n * t.K + k] = f2b(ldf(t.src, t.ebase + e, fm));
  }
}

// ---------------- fold att vectors into U matvec weights ----------------
// wallet cols j: 0,1=a_s type0 (h0,h1); 2,3=a_s type2; 4,5=a_d type1; 6,7=a_d type2
// token  cols jj: 0,1=a_s type1; 2,3=a_d type0
__global__ void uprep(const void* Wsrc0, const void* Wdst0, const void* atts0, const void* attd0,
                      const void* Wsrc1, const void* Wdst1, const void* atts1, const void* attd1,
                      float* Uw0, float* Ut0, float* Uw1, float* Ut1, const int* mode){
  int fm = mode[1];
  int id = blockIdx.x * 256 + threadIdx.x;
  if (id >= (64 + 128) * 12) return;
  int layer = (id >= 64 * 12);
  int rem = layer ? id - 64 * 12 : id;
  int K = layer ? 128 : 64;
  int k = rem / 12, j = rem % 12;
  const void* Ws = layer ? Wsrc1 : Wsrc0;
  const void* Wd = layer ? Wdst1 : Wdst0;
  const void* As = layer ? atts1 : atts0;
  const void* Ad = layer ? attd1 : attd0;
  int t, h; bool src;
  if (j < 8){ const int tt[8] = {0,0,2,2,1,1,2,2}; t = tt[j]; h = j & 1; src = (j < 4); }
  else { int jj = j - 8; t = (jj < 2) ? 1 : 0; h = jj & 1; src = (jj < 2); }
  const void* W = src ? Ws : Wd;
  const void* A = src ? As : Ad;
  float acc = 0.f;
  for (int c = 0; c < 64; ++c)
    acc += ldf(W, (long)(t * K + k) * 128 + h * 64 + c, fm) * ldf(A, t * 128 + h * 64 + c, fm);
  if (j < 8) (layer ? Uw1 : Uw0)[k * 8 + j] = acc;
  else       (layer ? Ut1 : Ut0)[k * 4 + (j - 8)] = acc;
}

// ---------------- CSR build ----------------
__global__ void hist_kern(const int* ewt, const int* etw, const int* eww, const int* mode, int* deg){
  int i = blockIdx.x * 256 + threadIdx.x;
  if (i >= 3 * EE) return;
  int md = mode[0];
  int t = i / EE, e = i - t * EE;
  const int* ep = (t == 0) ? ewt : (t == 1) ? etw : eww;
  int d = md ? ep[2 * (EE + e)] : ep[EE + e];
  int base = (t == 0) ? 0 : (t == 1) ? NT : NT + NW;
  atomicAdd(&deg[base + d], 1);
}

__global__ __launch_bounds__(512) void scan1(const int* deg, int* excl, int* sums){
  __shared__ int pair[512];
  int t = threadIdx.x;
  int base = blockIdx.x * 1024;
  int i0 = base + 2 * t;
  int a = (i0 < NSEG) ? deg[i0] : 0;
  int b = (i0 + 1 < NSEG) ? deg[i0 + 1] : 0;
  int ps = a + b;
  pair[t] = ps;
  __syncthreads();
  for (int off = 1; off < 512; off <<= 1){
    int v = (t >= off) ? pair[t - off] : 0;
    __syncthreads();
    if (t >= off) pair[t] += v;
    __syncthreads();
  }
  int epair = pair[t] - ps;
  if (i0 < NSEG) excl[i0] = epair;
  if (i0 + 1 < NSEG) excl[i0 + 1] = epair + a;
  if (t == 511) sums[blockIdx.x] = pair[511];
}

__global__ __launch_bounds__(512) void scan2(int* sums, int nch){
  __shared__ int s[512];
  int t = threadIdx.x;
  int orig = (t < nch) ? sums[t] : 0;
  s[t] = orig;
  __syncthreads();
  for (int off = 1; off < 512; off <<= 1){
    int v = (t >= off) ? s[t - off] : 0;
    __syncthreads();
    if (t >= off) s[t] += v;
    __syncthreads();
  }
  if (t < nch) sums[t] = s[t] - orig;
}

__global__ void scan3(int* rowptr, int* cursor, const int* sums){
  int i = blockIdx.x * 256 + threadIdx.x;
  if (i < NSEG){
    int v = rowptr[i] + sums[i >> 10];
    rowptr[i] = v; cursor[i] = v;
  }
  if (i == 0) rowptr[NSEG] = 3 * EE;
}

__global__ void fill_kern(const int* ewt, const int* etw, const int* eww, const int* mode,
                          int* cursor, int* adj){
  int i = blockIdx.x * 256 + threadIdx.x;
  if (i >= 3 * EE) return;
  int md = mode[0];
  int t = i / EE, e = i - t * EE;
  const int* ep = (t == 0) ? ewt : (t == 1) ? etw : eww;
  int s = md ? ep[2 * e] : ep[e];
  int d = md ? ep[2 * (EE + e)] : ep[EE + e];
  int base = (t == 0) ? 0 : (t == 1) ? NT : NT + NW;
  int pos = atomicAdd(&cursor[base + d], 1);
  adj[pos] = s;
}

// -------- B-stationary MFMA GEMM: C[M,NC] = A[M,K] @ Bt^T, Bt is [NC][K] bf16 --------
template<int K, int NC, bool BIAS, bool EXTA>
__global__ __launch_bounds__(256, 2) void gemm_kern(const void* __restrict__ A, const ushort_t* __restrict__ Bt,
    const void* __restrict__ bias, ushort_t* __restrict__ C, int M,
    const int* __restrict__ mode, int nchunk){
  constexpr int CT = NC / 16, KK = K / 32;
  int fm = EXTA ? mode[1] : 0;
  int tid = threadIdx.x, lane = tid & 63, wave = tid >> 6;
  int rl = lane & 15, kq = (lane >> 4) * 8;
  s8v bfrag[CT][KK];
#pragma unroll
  for (int ct = 0; ct < CT; ++ct)
#pragma unroll
    for (int kk = 0; kk < KK; ++kk)
      bfrag[ct][kk] = *(const s8v*)(Bt + (long)(ct * 16 + rl) * K + kk * 32 + kq);
  float biasv[CT];
  if (BIAS){
#pragma unroll
    for (int ct = 0; ct < CT; ++ct) biasv[ct] = ldf(bias, ct * 16 + rl, fm);
  }
  for (int chunk = blockIdx.x; chunk < nchunk; chunk += gridDim.x){
    long m0 = (long)chunk * 128 + wave * 32;
    f4v acc[2][CT];
#pragma unroll
    for (int rt = 0; rt < 2; ++rt)
#pragma unroll
      for (int ct = 0; ct < CT; ++ct) acc[rt][ct] = (f4v){0.f, 0.f, 0.f, 0.f};
#pragma unroll
    for (int rt = 0; rt < 2; ++rt){
      long row = m0 + rt * 16 + rl;
      bool ok = row < (long)M;
#pragma unroll
      for (int kk = 0; kk < KK; ++kk){
        s8v a = (s8v){0,0,0,0,0,0,0,0};
        if (ok){
          long e = row * K + kk * 32 + kq;
          if (EXTA && fm){
            const float* p = (const float*)A + e;
            uint4 lo = *(const uint4*)p;
            uint4 hi = *(const uint4*)(p + 4);
            union { s8v v; unsigned u[4]; } t;
            t.u[0] = (unsigned)f2b(__uint_as_float(lo.x)) | ((unsigned)f2b(__uint_as_float(lo.y)) << 16);
            t.u[1] = (unsigned)f2b(__uint_as_float(lo.z)) | ((unsigned)f2b(__uint_as_float(lo.w)) << 16);
            t.u[2] = (unsigned)f2b(__uint_as_float(hi.x)) | ((unsigned)f2b(__uint_as_float(hi.y)) << 16);
            t.u[3] = (unsigned)f2b(__uint_as_float(hi.z)) | ((unsigned)f2b(__uint_as_float(hi.w)) << 16);
            a = t.v;
          } else {
            a = *(const s8v*)((const ushort_t*)A + e);
          }
        }
#pragma unroll
        for (int ct = 0; ct < CT; ++ct)
          acc[rt][ct] = __builtin_amdgcn_mfma_f32_16x16x32_bf16(a, bfrag[ct][kk], acc[rt][ct], 0, 0, 0);
      }
    }
#pragma unroll
    for (int rt = 0; rt < 2; ++rt){
      long rbase = (long)chunk * 128 + wave * 32 + rt * 16 + (lane >> 4) * 4;
#pragma unroll
      for (int ct = 0; ct < CT; ++ct){
#pragma unroll
        for (int r = 0; r < 4; ++r){
          long gm = rbase + r;
          if (gm < (long)M){
            float v = acc[rt][ct][r];
            if (BIAS) v += biasv[ct];
            C[gm * NC + ct * 16 + rl] = f2b(v);
          }
        }
      }
    }
  }
}

// ------- per-node attention scalars, thread-per-node: out[N,NCOL] = x[N,K] @ U -------
template<int K, int NCOL>
__global__ __launch_bounds__(256) void a_kern(const ushort_t* __restrict__ x, const float* __restrict__ U,
                                              float* __restrict__ out, int N){
  int n = blockIdx.x * 256 + threadIdx.x;
  if (n >= N) return;
  float acc[NCOL];
#pragma unroll
  for (int j = 0; j < NCOL; ++j) acc[j] = 0.f;
  const ushort_t* xr = x + (long)n * K;
#pragma unroll
  for (int k8 = 0; k8 < K / 8; ++k8){
    uint4 v = *(const uint4*)(xr + k8 * 8);
    unsigned uu[4] = {v.x, v.y, v.z, v.w};
#pragma unroll
    for (int i = 0; i < 4; ++i){
      float f0 = b2f((unsigned short)(uu[i] & 0xffffu));
      float f1 = b2f((unsigned short)(uu[i] >> 16));
      const float* Ur = U + (k8 * 8 + i * 2) * NCOL;
#pragma unroll
      for (int j = 0; j < NCOL; ++j) acc[j] += f0 * Ur[j] + f1 * Ur[NCOL + j];
    }
  }
  f4v* o4 = (f4v*)(out + (long)n * NCOL);
#pragma unroll
  for (int q = 0; q < NCOL / 4; ++q){
    f4v t = {acc[q * 4], acc[q * 4 + 1], acc[q * 4 + 2], acc[q * 4 + 3]};
    o4[q] = t;
  }
}

// ------- per-node softmax, single-pass register-buffered (deg<=8), writes NORMALIZED weights -------
__global__ __launch_bounds__(256) void node_softmax(const int* __restrict__ rowptr,
    const int* __restrict__ adj, const float* __restrict__ aw, const float* __restrict__ at,
    float2* __restrict__ alf){
  int seg = blockIdx.x * 256 + threadIdx.x;
  if (seg >= NSEG) return;
  int beg = rowptr[seg], end = rowptr[seg + 1];
  int n = end - beg;
  if (n <= 0) return;
  const float* asrc; int stride, col; float2 ad;
  if (seg < NT){            // type0: wallet -> token
    asrc = aw; stride = 8; col = 0;
    ad = *(const float2*)(at + (long)seg * 4 + 2);
  } else if (seg < NT + NW){ // type1: token -> wallet
    asrc = at; stride = 4; col = 0;
    ad = *(const float2*)(aw + (long)(seg - NT) * 8 + 4);
  } else {                  // type2: wallet -> wallet
    asrc = aw; stride = 8; col = 2;
    ad = *(const float2*)(aw + (long)(seg - NT - NW) * 8 + 6);
  }
  if (n <= 8){
    float2 buf[8];
    float m0 = -1e30f, m1 = -1e30f;
#pragma unroll
    for (int i = 0; i < 8; ++i){
      if (i < n){
        int s = adj[beg + i];
        float2 x = *(const float2*)(asrc + (long)s * stride + col);
        float a0 = x.x + ad.x, a1 = x.y + ad.y;
        a0 = a0 > 0.f ? a0 : 0.2f * a0;
        a1 = a1 > 0.f ? a1 : 0.2f * a1;
        buf[i] = make_float2(a0, a1);
        m0 = fmaxf(m0, a0); m1 = fmaxf(m1, a1);
      }
    }
    float d0 = 0.f, d1 = 0.f;
#pragma unroll
    for (int i = 0; i < 8; ++i){
      if (i < n){
        float w0 = __expf(buf[i].x - m0), w1 = __expf(buf[i].y - m1);
        d0 += w0; d1 += w1;
        buf[i] = make_float2(w0, w1);
      }
    }
    float i0 = 1.f / (d0 + 1e-16f), i1 = 1.f / (d1 + 1e-16f);
#pragma unroll
    for (int i = 0; i < 8; ++i)
      if (i < n) alf[beg + i] = make_float2(buf[i].x * i0, buf[i].y * i1);
  } else {
    // rare long-degree fallback: 3 passes
    float m0 = -1e30f, m1 = -1e30f;
    for (int j = beg; j < end; ++j){
      int s = adj[j];
      float2 x = *(const float2*)(asrc + (long)s * stride + col);
      float a0 = x.x + ad.x, a1 = x.y + ad.y;
      a0 = a0 > 0.f ? a0 : 0.2f * a0;
      a1 = a1 > 0.f ? a1 : 0.2f * a1;
      alf[j] = make_float2(a0, a1);
      m0 = fmaxf(m0, a0); m1 = fmaxf(m1, a1);
    }
    float d0 = 0.f, d1 = 0.f;
    for (int j = beg; j < end; ++j){
      float2 a = alf[j];
      a.x = __expf(a.x - m0); a.y = __expf(a.y - m1);
      d0 += a.x; d1 += a.y;
      alf[j] = a;
    }
    float i0 = 1.f / (d0 + 1e-16f), i1 = 1.f / (d1 + 1e-16f);
    for (int j = beg; j < end; ++j){
      float2 a = alf[j];
      alf[j] = make_float2(a.x * i0, a.y * i1);
    }
  }
}

// ------- batch-8 gather: issue ALL loads for a round before any accumulation -------
// adj/alf indices are wave-uniform -> scalar loads (weights live in SGPRs);
// h loads are the only per-lane traffic (4B/lane = 256B/wave, coalesced).
__device__ __forceinline__ void gather8(const int* __restrict__ adj, const float2* __restrict__ alf,
    int j, int end, const ushort_t* __restrict__ hs, int c0,
    unsigned (&h)[8], float2 (&w)[8]){
#pragma unroll
  for (int i = 0; i < 8; ++i){
    int jc = (j + i < end) ? j + i : end - 1;   // clamp: dup load is an L1 hit
    int s = adj[jc];
    w[i] = alf[jc];
    h[i] = *(const unsigned*)(hs + (long)s * 128 + c0);
  }
}
__device__ __forceinline__ void acc8(int j, int end, const unsigned (&h)[8], const float2 (&w)[8],
    int lane, float& o0, float& o1){
#pragma unroll
  for (int i = 0; i < 8; ++i){
    float v = (lane < 32) ? w[i].x : w[i].y;
    float wl = (j + i < end) ? v : 0.f;         // zero pad slots
    o0 += wl * b2f((unsigned short)(h[i] & 0xffffu));
    o1 += wl * b2f((unsigned short)(h[i] >> 16));
  }
}

// ------- merged agg: blocks [0,NT/4) = token nodes, rest = wallet nodes -------
// Token: one batch-8 round covers deg<=8 (~93%); wallet: BOTH edge-type streams'
// first rounds issued back-to-back (16 gathers in flight) -> one memory round-trip
// for ~99.8% of wallet nodes instead of 2-4 serialized rounds.
// FINAL: classifier fused, writes 2 logits/node instead of 256B hidden row.
template<bool FINAL>
__global__ __launch_bounds__(256) void agg_all(const int* __restrict__ rowptr, const int* __restrict__ adj,
    const float2* __restrict__ alf,
    const ushort_t* __restrict__ hs0, const ushort_t* __restrict__ hs1, const ushort_t* __restrict__ hs2,
    const void* __restrict__ bsrc, ushort_t* __restrict__ xt_out, ushort_t* __restrict__ xw_out,
    const void* __restrict__ clsWw, const void* __restrict__ clsbw,
    const void* __restrict__ clsWt, const void* __restrict__ clsbt,
    void* __restrict__ dout, const int* __restrict__ mode){
  int fm = mode[1];
  int wv = __builtin_amdgcn_readfirstlane(threadIdx.x >> 6);  // wave-uniform
  int lane = threadIdx.x & 63;
  int c0 = lane << 1;
  int bid = blockIdx.x;
  const int TB = NT / 4;
  float o0 = 0.f, o1 = 0.f;
  bool is_tok = bid < TB;
  int d;
  if (is_tok){
    d = bid * 4 + wv;
    o0 += ldf(bsrc, c0, fm);
    o1 += ldf(bsrc, c0 + 1, fm);
    int beg = rowptr[d], end = rowptr[d + 1];
    for (int j = beg; j < end; j += 8){
      unsigned h[8]; float2 w[8];
      gather8(adj, alf, j, end, hs0, c0, h, w);
      acc8(j, end, h, w, lane, o0, o1);
    }
  } else {
    d = (bid - TB) * 4 + wv;
    o0 += ldf(bsrc, 128 + c0, fm)     + ldf(bsrc, 256 + c0, fm);
    o1 += ldf(bsrc, 128 + c0 + 1, fm) + ldf(bsrc, 256 + c0 + 1, fm);
    int s1 = NT + d, s2 = NT + NW + d;
    int b1 = rowptr[s1], e1 = rowptr[s1 + 1];
    int b2 = rowptr[s2], e2 = rowptr[s2 + 1];
    bool r1 = b1 < e1, r2 = b2 < e2;
    // fused first rounds: all loads of both streams in flight before accumulating
    unsigned h1[8], h2[8]; float2 w1[8], w2[8];
    if (r1) gather8(adj, alf, b1, e1, hs1, c0, h1, w1);
    if (r2) gather8(adj, alf, b2, e2, hs2, c0, h2, w2);
    if (r1) acc8(b1, e1, h1, w1, lane, o0, o1);
    if (r2) acc8(b2, e2, h2, w2, lane, o0, o1);
    // rare tails (deg > 8)
    for (int j = b1 + 8; j < e1; j += 8){
      unsigned h[8]; float2 w[8];
      gather8(adj, alf, j, e1, hs1, c0, h, w);
      acc8(j, e1, h, w, lane, o0, o1);
    }
    for (int j = b2 + 8; j < e2; j += 8){
      unsigned h[8]; float2 w[8];
      gather8(adj, alf, j, e2, hs2, c0, h, w);
      acc8(j, e2, h, w, lane, o0, o1);
    }
  }
  o0 = o0 > 0.f ? o0 : __expf(o0) - 1.f;   // ELU (2-ulp exp fine under bf16 rounding)
  o1 = o1 > 0.f ? o1 : __expf(o1) - 1.f;
  if (!FINAL){
    ushort_t* out = is_tok ? xt_out : xw_out;
    unsigned pack = (unsigned)f2b(o0) | ((unsigned)f2b(o1) << 16);
    *(unsigned*)(out + (long)d * 128 + c0) = pack;
  } else {
    const void* W = is_tok ? clsWt : clsWw;
    const void* b = is_tok ? clsbt : clsbw;
    float w00 = ldf(W, 4 * lane + 0, fm), w01 = ldf(W, 4 * lane + 1, fm);
    float w10 = ldf(W, 4 * lane + 2, fm), w11 = ldf(W, 4 * lane + 3, fm);
    float p0 = o0 * w00 + o1 * w10;
    float p1 = o0 * w01 + o1 * w11;
#pragma unroll
    for (int off = 32; off > 0; off >>= 1){ p0 += __shfl_xor(p0, off, 64); p1 += __shfl_xor(p1, off, 64); }
    if (lane == 0){
      long g = is_tok ? (long)NW + d : (long)d;
      float r0 = p0 + ldf(b, 0, fm);
      float r1 = p1 + ldf(b, 1, fm);
      if (fm){ ((float*)dout)[g * 2] = r0; ((float*)dout)[g * 2 + 1] = r1; }
      else { ((ushort_t*)dout)[g * 2] = f2b(r0); ((ushort_t*)dout)[g * 2 + 1] = f2b(r1); }
    }
  }
}

extern "C" void kernel_launch(void* const* d_in, const int* in_sizes, int n_in,
                              void* d_out, int out_size, void* d_ws, size_t ws_size,
                              hipStream_t stream){
  const void* x_wallet = d_in[0];
  const void* x_token  = d_in[1];
  const void* lin_w_W  = d_in[2];
  const void* lin_w_b  = d_in[3];
  const void* lin_t_W  = d_in[4];
  const void* lin_t_b  = d_in[5];
  const void* Wsrc0    = d_in[6];
  const void* Wdst0    = d_in[7];
  const void* atts0    = d_in[8];
  const void* attd0    = d_in[9];
  const void* b0       = d_in[10];
  const void* Wsrc1    = d_in[11];
  const void* Wdst1    = d_in[12];
  const void* atts1    = d_in[13];
  const void* attd1    = d_in[14];
  const void* b1       = d_in[15];
  const void* cls_w_W  = d_in[16];
  const void* cls_w_b  = d_in[17];
  const void* cls_t_W  = d_in[18];
  const void* cls_t_b  = d_in[19];
  const int* e_wt = (const int*)d_in[20];
  const int* e_tw = (const int*)d_in[21];
  const int* e_ww = (const int*)d_in[22];

  char* ws = (char*)d_ws;
  size_t off = 0;
  auto alloc = [&](size_t bytes) -> char* {
    char* p = ws + off; off += (bytes + 255) & ~(size_t)255; return p;
  };
  int* rowptr = (int*)alloc((size_t)(NSEG + 1) * 4);
  int* deg    = (int*)alloc((size_t)(NSEG + 1) * 4);   // doubles as fill cursor after scan
  int* adj    = (int*)alloc((size_t)3 * EE * 4);
  float2* alf = (float2*)alloc((size_t)3 * EE * 8);
  int* sums   = (int*)alloc(512 * 4);
  int* mode   = (int*)alloc(8);
  ushort_t* BtLw = (ushort_t*)alloc(64 * 128 * 2);
  ushort_t* BtLt = (ushort_t*)alloc(64 * 64 * 2);
  ushort_t* BtS0 = (ushort_t*)alloc(3 * 128 * 64 * 2);
  ushort_t* BtS1 = (ushort_t*)alloc(3 * 128 * 128 * 2);
  float* Uw0 = (float*)alloc(64 * 8 * 4);
  float* Ut0 = (float*)alloc(64 * 4 * 4);
  float* Uw1 = (float*)alloc(128 * 8 * 4);
  float* Ut1 = (float*)alloc(128 * 4 * 4);
  float* aw = (float*)alloc((size_t)NW * 8 * 4);
  float* at = (float*)alloc((size_t)NT * 4 * 4);
  ushort_t* hs0 = (ushort_t*)alloc((size_t)NW * 128 * 2);
  ushort_t* hs1 = (ushort_t*)alloc((size_t)NT * 128 * 2);
  ushort_t* hs2 = (ushort_t*)alloc((size_t)NW * 128 * 2);
  ushort_t* xbuf = (ushort_t*)alloc(((size_t)NW + NT) * 128 * 2);
  ushort_t* xw0 = xbuf;
  ushort_t* xt0 = xbuf + (size_t)NW * 64;
  ushort_t* xwB = xbuf;                         // aliases xw0+xt0 (both dead by then)
  ushort_t* xtB = xbuf + (size_t)NW * 128;      // disjoint from xw0/xt0
  (void)in_sizes; (void)n_in;

  if (off > ws_size){
    hipMemsetAsync(d_out, 0, (size_t)out_size * 2, stream);
    return;
  }

  hipMemsetAsync(deg, 0, (size_t)NSEG * 4, stream);
  detect_kern<<<1, 64, 0, stream>>>(e_wt, e_tw, e_ww, (const unsigned*)x_wallet, mode);

  TDesc8 td;
  td.d[0] = { lin_w_W, BtLw, 0, 128, 64 };
  td.d[1] = { lin_t_W, BtLt, 0, 64, 64 };
  for (int t = 0; t < 3; ++t){
    td.d[2 + t] = { Wsrc0, BtS0 + t * 128 * 64,  (long)t * 64 * 128,  64,  128 };
    td.d[5 + t] = { Wsrc1, BtS1 + t * 128 * 128, (long)t * 128 * 128, 128, 128 };
  }
  transpose8<<<512, 256, 0, stream>>>(td, mode);
  uprep<<<9, 256, 0, stream>>>(Wsrc0, Wdst0, atts0, attd0, Wsrc1, Wdst1, atts1, attd1, Uw0, Ut0, Uw1, Ut1, mode);

  int egrid = (3 * EE + 255) / 256;
  hist_kern<<<egrid, 256, 0, stream>>>(e_wt, e_tw, e_ww, mode, deg);
  int nch = (NSEG + 1023) / 1024;
  scan1<<<nch, 512, 0, stream>>>(deg, rowptr, sums);
  scan2<<<1, 512, 0, stream>>>(sums, nch);
  scan3<<<(NSEG + 255) / 256, 256, 0, stream>>>(rowptr, deg, sums);   // deg becomes cursor
  fill_kern<<<egrid, 256, 0, stream>>>(e_wt, e_tw, e_ww, mode, deg, adj);

  const int G = 512;
  int ncW = (NW + 127) / 128, ncT = (NT + 127) / 128;
  int sgrid = (NSEG + 255) / 256;
  int agrid = NT / 4 + NW / 4;

  // input projections (external A, dtype per mode[1])
  gemm_kern<128, 64, true, true><<<G, 256, 0, stream>>>(x_wallet, BtLw, lin_w_b, xw0, NW, mode, ncW);
  gemm_kern<64, 64, true, true><<<G, 256, 0, stream>>>(x_token, BtLt, lin_t_b, xt0, NT, mode, ncT);

  // ---- layer 0 (K=64) ----
  a_kern<64, 8><<<(NW + 255) / 256, 256, 0, stream>>>(xw0, Uw0, aw, NW);
  a_kern<64, 4><<<(NT + 255) / 256, 256, 0, stream>>>(xt0, Ut0, at, NT);
  node_softmax<<<sgrid, 256, 0, stream>>>(rowptr, adj, aw, at, alf);
  gemm_kern<64, 128, false, false><<<G, 256, 0, stream>>>(xw0, BtS0, nullptr, hs0, NW, mode, ncW);
  gemm_kern<64, 128, false, false><<<G, 256, 0, stream>>>(xt0, BtS0 + 128 * 64, nullptr, hs1, NT, mode, ncT);
  gemm_kern<64, 128, false, false><<<G, 256, 0, stream>>>(xw0, BtS0 + 2 * 128 * 64, nullptr, hs2, NW, mode, ncW);
  agg_all<false><<<agrid, 256, 0, stream>>>(rowptr, adj, alf, hs0, hs1, hs2, b0, xtB, xwB,
                                            nullptr, nullptr, nullptr, nullptr, nullptr, mode);

  // ---- layer 1 (K=128), classifier fused ----
  a_kern<128, 8><<<(NW + 255) / 256, 256, 0, stream>>>(xwB, Uw1, aw, NW);
  a_kern<128, 4><<<(NT + 255) / 256, 256, 0, stream>>>(xtB, Ut1, at, NT);
  node_softmax<<<sgrid, 256, 0, stream>>>(rowptr, adj, aw, at, alf);
  gemm_kern<128, 128, false, false><<<G, 256, 0, stream>>>(xwB, BtS1, nullptr, hs0, NW, mode, ncW);
  gemm_kern<128, 128, false, false><<<G, 256, 0, stream>>>(xtB, BtS1 + 128 * 128, nullptr, hs1, NT, mode, ncT);
  gemm_kern<128, 128, false, false><<<G, 256, 0, stream>>>(xwB, BtS1 + 2 * 128 * 128, nullptr, hs2, NW, mode, ncW);
  agg_all<true><<<agrid, 256, 0, stream>>>(rowptr, adj, alf, hs0, hs1, hs2, b1, nullptr, nullptr,
                                           cls_w_W, cls_w_b, cls_t_W, cls_t_b, d_out, mode);
}

// Round 2
// 924.701 us; speedup vs baseline: 1.0377x; 1.0377x over previous
//
#include <hip/hip_runtime.h>
#include <stdint.h>

typedef unsigned short ushort_t;
typedef short s8v __attribute__((ext_vector_type(8)));
typedef float f4v __attribute__((ext_vector_type(4)));

#define NW 200000
#define NT 100000
#define EE 500000
#define NSEG (NT + NW + NW)   // concatenated dst slots: [tok(e_wt) | wal(e_tw) | wal(e_ww)]

__device__ __forceinline__ float b2f(unsigned short u){
  union { unsigned int i; float f; } v; v.i = ((unsigned int)u) << 16; return v.f;
}
__device__ __forceinline__ unsigned short f2b(float f){
  unsigned int x = __float_as_uint(f);
  unsigned int r = x + 0x7fffu + ((x >> 16) & 1u);   // RNE
  return (unsigned short)(r >> 16);
}
__device__ __forceinline__ float ldf(const void* p, long idx, int fm){
  return fm ? ((const float*)p)[idx] : b2f(((const ushort_t*)p)[idx]);
}

// ---------------- runtime dtype probes ----------------
// mode[0]: 1 = edges are int64, 0 = int32 ; mode[1]: 1 = floats are fp32, 0 = bf16
__global__ void detect_kern(const int* ewt, const int* etw, const int* eww,
                            const unsigned* xw_words, int* mode){
  if (threadIdx.x == 0 && blockIdx.x == 0){
    unsigned o = 0;
    for (int i = 0; i < 64; ++i)
      o |= (unsigned)ewt[2 * i + 1] | (unsigned)etw[2 * i + 1] | (unsigned)eww[2 * i + 1];
    mode[0] = (o == 0) ? 1 : 0;
    int viol = 0;
    for (int i = 0; i < 256; ++i){
      unsigned s = xw_words[i] & 0xffffu;
      unsigned e = (s >> 7) & 0xffu;
      if (!(s == 0u || s == 0x8000u || (e >= 90u && e <= 140u))) viol++;
    }
    mode[1] = (viol > 8) ? 1 : 0;
  }
}

// ------ batched weight transpose+convert: dst[n*K+k] = bf16(src[ebase + k*N + n]) ------
struct TDesc { const void* src; ushort_t* dst; long ebase; int K; int N; };
struct TDesc8 { TDesc d[8]; };
__global__ void transpose8(TDesc8 td, const int* mode){
  int fm = mode[1];
  int mi = blockIdx.x >> 6;
  TDesc t = td.d[mi];
  int e = ((blockIdx.x & 63) << 8) + threadIdx.x;
  if (e < t.K * t.N){
    int k = e / t.N, n = e - k * t.N;
    t.dst[n * t.K + k] = f2b(ldf(t.src, t.ebase + e, fm));
  }
}

// ---------------- fold att vectors into U matvec weights ----------------
// wallet cols j: 0,1=a_s type0 (h0,h1); 2,3=a_s type2; 4,5=a_d type1; 6,7=a_d type2
// token  cols jj: 0,1=a_s type1; 2,3=a_d type0
__global__ void uprep(const void* Wsrc0, const void* Wdst0, const void* atts0, const void* attd0,
                      const void* Wsrc1, const void* Wdst1, const void* atts1, const void* attd1,
                      float* Uw0, float* Ut0, float* Uw1, float* Ut1, const int* mode){
  int fm = mode[1];
  int id = blockIdx.x * 256 + threadIdx.x;
  if (id >= (64 + 128) * 12) return;
  int layer = (id >= 64 * 12);
  int rem = layer ? id - 64 * 12 : id;
  int K = layer ? 128 : 64;
  int k = rem / 12, j = rem % 12;
  const void* Ws = layer ? Wsrc1 : Wsrc0;
  const void* Wd = layer ? Wdst1 : Wdst0;
  const void* As = layer ? atts1 : atts0;
  const void* Ad = layer ? attd1 : attd0;
  int t, h; bool src;
  if (j < 8){ const int tt[8] = {0,0,2,2,1,1,2,2}; t = tt[j]; h = j & 1; src = (j < 4); }
  else { int jj = j - 8; t = (jj < 2) ? 1 : 0; h = jj & 1; src = (jj < 2); }
  const void* W = src ? Ws : Wd;
  const void* A = src ? As : Ad;
  float acc = 0.f;
  for (int c = 0; c < 64; ++c)
    acc += ldf(W, (long)(t * K + k) * 128 + h * 64 + c, fm) * ldf(A, t * 128 + h * 64 + c, fm);
  if (j < 8) (layer ? Uw1 : Uw0)[k * 8 + j] = acc;
  else       (layer ? Ut1 : Ut0)[k * 4 + (j - 8)] = acc;
}

// ---------------- CSR build ----------------
__global__ void hist_kern(const int* ewt, const int* etw, const int* eww, const int* mode, int* deg){
  int i = blockIdx.x * 256 + threadIdx.x;
  if (i >= 3 * EE) return;
  int md = mode[0];
  int t = i / EE, e = i - t * EE;
  const int* ep = (t == 0) ? ewt : (t == 1) ? etw : eww;
  int d = md ? ep[2 * (EE + e)] : ep[EE + e];
  int base = (t == 0) ? 0 : (t == 1) ? NT : NT + NW;
  atomicAdd(&deg[base + d], 1);
}

__global__ __launch_bounds__(512) void scan1(const int* deg, int* excl, int* sums){
  __shared__ int pair[512];
  int t = threadIdx.x;
  int base = blockIdx.x * 1024;
  int i0 = base + 2 * t;
  int a = (i0 < NSEG) ? deg[i0] : 0;
  int b = (i0 + 1 < NSEG) ? deg[i0 + 1] : 0;
  int ps = a + b;
  pair[t] = ps;
  __syncthreads();
  for (int off = 1; off < 512; off <<= 1){
    int v = (t >= off) ? pair[t - off] : 0;
    __syncthreads();
    if (t >= off) pair[t] += v;
    __syncthreads();
  }
  int epair = pair[t] - ps;
  if (i0 < NSEG) excl[i0] = epair;
  if (i0 + 1 < NSEG) excl[i0 + 1] = epair + a;
  if (t == 511) sums[blockIdx.x] = pair[511];
}

__global__ __launch_bounds__(512) void scan2(int* sums, int nch){
  __shared__ int s[512];
  int t = threadIdx.x;
  int orig = (t < nch) ? sums[t] : 0;
  s[t] = orig;
  __syncthreads();
  for (int off = 1; off < 512; off <<= 1){
    int v = (t >= off) ? s[t - off] : 0;
    __syncthreads();
    if (t >= off) s[t] += v;
    __syncthreads();
  }
  if (t < nch) sums[t] = s[t] - orig;
}

__global__ void scan3(int* rowptr, int* cursor, const int* sums){
  int i = blockIdx.x * 256 + threadIdx.x;
  if (i < NSEG){
    int v = rowptr[i] + sums[i >> 10];
    rowptr[i] = v; cursor[i] = v;
  }
  if (i == 0) rowptr[NSEG] = 3 * EE;
}

__global__ void fill_kern(const int* ewt, const int* etw, const int* eww, const int* mode,
                          int* cursor, int* adj){
  int i = blockIdx.x * 256 + threadIdx.x;
  if (i >= 3 * EE) return;
  int md = mode[0];
  int t = i / EE, e = i - t * EE;
  const int* ep = (t == 0) ? ewt : (t == 1) ? etw : eww;
  int s = md ? ep[2 * e] : ep[e];
  int d = md ? ep[2 * (EE + e)] : ep[EE + e];
  int base = (t == 0) ? 0 : (t == 1) ? NT : NT + NW;
  int pos = atomicAdd(&cursor[base + d], 1);
  adj[pos] = s;
}

// -------- B-stationary MFMA GEMM: C[M,NC] = A[M,K] @ Bt^T, Bt is [NC][K] bf16 --------
template<int K, int NC, bool BIAS, bool EXTA>
__global__ __launch_bounds__(256, 2) void gemm_kern(const void* __restrict__ A, const ushort_t* __restrict__ Bt,
    const void* __restrict__ bias, ushort_t* __restrict__ C, int M,
    const int* __restrict__ mode, int nchunk){
  constexpr int CT = NC / 16, KK = K / 32;
  int fm = EXTA ? mode[1] : 0;
  int tid = threadIdx.x, lane = tid & 63, wave = tid >> 6;
  int rl = lane & 15, kq = (lane >> 4) * 8;
  s8v bfrag[CT][KK];
#pragma unroll
  for (int ct = 0; ct < CT; ++ct)
#pragma unroll
    for (int kk = 0; kk < KK; ++kk)
      bfrag[ct][kk] = *(const s8v*)(Bt + (long)(ct * 16 + rl) * K + kk * 32 + kq);
  float biasv[CT];
  if (BIAS){
#pragma unroll
    for (int ct = 0; ct < CT; ++ct) biasv[ct] = ldf(bias, ct * 16 + rl, fm);
  }
  for (int chunk = blockIdx.x; chunk < nchunk; chunk += gridDim.x){
    long m0 = (long)chunk * 128 + wave * 32;
    f4v acc[2][CT];
#pragma unroll
    for (int rt = 0; rt < 2; ++rt)
#pragma unroll
      for (int ct = 0; ct < CT; ++ct) acc[rt][ct] = (f4v){0.f, 0.f, 0.f, 0.f};
#pragma unroll
    for (int rt = 0; rt < 2; ++rt){
      long row = m0 + rt * 16 + rl;
      bool ok = row < (long)M;
#pragma unroll
      for (int kk = 0; kk < KK; ++kk){
        s8v a = (s8v){0,0,0,0,0,0,0,0};
        if (ok){
          long e = row * K + kk * 32 + kq;
          if (EXTA && fm){
            const float* p = (const float*)A + e;
            uint4 lo = *(const uint4*)p;
            uint4 hi = *(const uint4*)(p + 4);
            union { s8v v; unsigned u[4]; } t;
            t.u[0] = (unsigned)f2b(__uint_as_float(lo.x)) | ((unsigned)f2b(__uint_as_float(lo.y)) << 16);
            t.u[1] = (unsigned)f2b(__uint_as_float(lo.z)) | ((unsigned)f2b(__uint_as_float(lo.w)) << 16);
            t.u[2] = (unsigned)f2b(__uint_as_float(hi.x)) | ((unsigned)f2b(__uint_as_float(hi.y)) << 16);
            t.u[3] = (unsigned)f2b(__uint_as_float(hi.z)) | ((unsigned)f2b(__uint_as_float(hi.w)) << 16);
            a = t.v;
          } else {
            a = *(const s8v*)((const ushort_t*)A + e);
          }
        }
#pragma unroll
        for (int ct = 0; ct < CT; ++ct)
          acc[rt][ct] = __builtin_amdgcn_mfma_f32_16x16x32_bf16(a, bfrag[ct][kk], acc[rt][ct], 0, 0, 0);
      }
    }
#pragma unroll
    for (int rt = 0; rt < 2; ++rt){
      long rbase = (long)chunk * 128 + wave * 32 + rt * 16 + (lane >> 4) * 4;
#pragma unroll
      for (int ct = 0; ct < CT; ++ct){
#pragma unroll
        for (int r = 0; r < 4; ++r){
          long gm = rbase + r;
          if (gm < (long)M){
            float v = acc[rt][ct][r];
            if (BIAS) v += biasv[ct];
            C[gm * NC + ct * 16 + rl] = f2b(v);
          }
        }
      }
    }
  }
}

// ------- per-node attention scalars, thread-per-node: out[N,NCOL] = x[N,K] @ U -------
template<int K, int NCOL>
__global__ __launch_bounds__(256) void a_kern(const ushort_t* __restrict__ x, const float* __restrict__ U,
                                              float* __restrict__ out, int N){
  int n = blockIdx.x * 256 + threadIdx.x;
  if (n >= N) return;
  float acc[NCOL];
#pragma unroll
  for (int j = 0; j < NCOL; ++j) acc[j] = 0.f;
  const ushort_t* xr = x + (long)n * K;
#pragma unroll
  for (int k8 = 0; k8 < K / 8; ++k8){
    uint4 v = *(const uint4*)(xr + k8 * 8);
    unsigned uu[4] = {v.x, v.y, v.z, v.w};
#pragma unroll
    for (int i = 0; i < 4; ++i){
      float f0 = b2f((unsigned short)(uu[i] & 0xffffu));
      float f1 = b2f((unsigned short)(uu[i] >> 16));
      const float* Ur = U + (k8 * 8 + i * 2) * NCOL;
#pragma unroll
      for (int j = 0; j < NCOL; ++j) acc[j] += f0 * Ur[j] + f1 * Ur[NCOL + j];
    }
  }
  f4v* o4 = (f4v*)(out + (long)n * NCOL);
#pragma unroll
  for (int q = 0; q < NCOL / 4; ++q){
    f4v t = {acc[q * 4], acc[q * 4 + 1], acc[q * 4 + 2], acc[q * 4 + 3]};
    o4[q] = t;
  }
}

// ------- exact-count gather round (wave-uniform cnt; no dup loads, no zero-FMA) -------
// Loads adj (scalar), per-edge att scalars (broadcast 8B) and hidden row word (4B/lane,
// 256B/wave coalesced) for up to 8 edges, ALL issued before any use.
__device__ __forceinline__ void round_load(const int* __restrict__ adj,
    const float* __restrict__ asrc, int stride, int col, int j, int cnt,
    const ushort_t* __restrict__ hs, int c0, float2 (&av)[8], unsigned (&h)[8]){
#pragma unroll
  for (int i = 0; i < 8; ++i){
    if (i < cnt){
      int s = adj[j + i];
      av[i] = *(const float2*)(asrc + (long)s * stride + col);
      h[i] = *(const unsigned*)(hs + (long)s * 128 + c0);
    }
  }
}

// ------- online-softmax accumulate: leaky-relu attention, running max/den rescale -------
__device__ __forceinline__ void round_acc(int cnt, float adl, int hi,
    const float2 (&av)[8], const unsigned (&h)[8],
    float& n0, float& n1, float& den, float& mm){
  float al[8];
  float rm = -1e30f;
#pragma unroll
  for (int i = 0; i < 8; ++i){
    if (i < cnt){
      float x = (hi ? av[i].y : av[i].x) + adl;
      x = x > 0.f ? x : 0.2f * x;
      al[i] = x;
      rm = fmaxf(rm, x);
    }
  }
  float mnew = fmaxf(mm, rm);
  float sc = __expf(mm - mnew);     // 0 on first round (mm = -1e30)
  n0 *= sc; n1 *= sc; den *= sc; mm = mnew;
#pragma unroll
  for (int i = 0; i < 8; ++i){
    if (i < cnt){
      float e = __expf(al[i] - mnew);
      den += e;
      n0 += e * b2f((unsigned short)(h[i] & 0xffffu));
      n1 += e * b2f((unsigned short)(h[i] >> 16));
    }
  }
}

// ------- merged agg with FUSED softmax: blocks [0,NT/4) = token nodes, rest = wallet -------
// Each wave owns one dst node; softmax is computed inline (online) from aw/at scalars
// gathered in the SAME memory round as the hidden rows -> node_softmax pass eliminated.
// Wallet: both edge-type streams' first rounds issued back-to-back (loads fused).
// FINAL: classifier fused, writes 2 logits/node.
template<bool FINAL>
__global__ __launch_bounds__(256) void agg_all(const int* __restrict__ rowptr, const int* __restrict__ adj,
    const float* __restrict__ aw, const float* __restrict__ at,
    const ushort_t* __restrict__ hs0, const ushort_t* __restrict__ hs1, const ushort_t* __restrict__ hs2,
    const void* __restrict__ bsrc, ushort_t* __restrict__ xt_out, ushort_t* __restrict__ xw_out,
    const void* __restrict__ clsWw, const void* __restrict__ clsbw,
    const void* __restrict__ clsWt, const void* __restrict__ clsbt,
    void* __restrict__ dout, const int* __restrict__ mode){
  int fm = mode[1];
  int wv = __builtin_amdgcn_readfirstlane(threadIdx.x >> 6);  // wave-uniform
  int lane = threadIdx.x & 63;
  int hi = lane >> 5;          // head select: lanes 0-31 head0, 32-63 head1
  int c0 = lane << 1;
  int bid = blockIdx.x;
  const int TB = NT / 4;
  bool is_tok = bid < TB;
  float o0, o1;
  int d;
  if (is_tok){
    d = bid * 4 + wv;
    float2 ad = *(const float2*)(at + (long)d * 4 + 2);   // a_d type0
    float adl = hi ? ad.y : ad.x;
    int beg = rowptr[d], end = rowptr[d + 1];
    float n0 = 0.f, n1 = 0.f, den = 0.f, mm = -1e30f;
    for (int j = beg; j < end; j += 8){
      int cnt = min(end - j, 8);
      float2 av[8]; unsigned h[8];
      round_load(adj, aw, 8, 0, j, cnt, hs0, c0, av, h);  // a_s type0 = aw cols 0,1
      round_acc(cnt, adl, hi, av, h, n0, n1, den, mm);
    }
    float inv = 1.f / (den + 1e-16f);
    o0 = n0 * inv + ldf(bsrc, c0, fm);
    o1 = n1 * inv + ldf(bsrc, c0 + 1, fm);
  } else {
    d = (bid - TB) * 4 + wv;
    float2 ad1 = *(const float2*)(aw + (long)d * 8 + 4);  // a_d type1
    float2 ad2 = *(const float2*)(aw + (long)d * 8 + 6);  // a_d type2
    float adl1 = hi ? ad1.y : ad1.x;
    float adl2 = hi ? ad2.y : ad2.x;
    int s1 = NT + d, s2 = NT + NW + d;
    int b1 = rowptr[s1], e1 = rowptr[s1 + 1];
    int b2 = rowptr[s2], e2 = rowptr[s2 + 1];
    int c1 = min(e1 - b1, 8), c2 = min(e2 - b2, 8);
    float n10 = 0.f, n11 = 0.f, den1 = 0.f, mm1 = -1e30f;
    float n20 = 0.f, n21 = 0.f, den2 = 0.f, mm2 = -1e30f;
    {
      // fused first rounds: all loads of both streams in flight before accumulating
      float2 av1[8], av2[8]; unsigned h1[8], h2[8];
      if (c1 > 0) round_load(adj, at, 4, 0, b1, c1, hs1, c0, av1, h1);  // a_s type1 = at cols 0,1
      if (c2 > 0) round_load(adj, aw, 8, 2, b2, c2, hs2, c0, av2, h2);  // a_s type2 = aw cols 2,3
      if (c1 > 0) round_acc(c1, adl1, hi, av1, h1, n10, n11, den1, mm1);
      if (c2 > 0) round_acc(c2, adl2, hi, av2, h2, n20, n21, den2, mm2);
    }
    for (int j = b1 + 8; j < e1; j += 8){   // rare tails (deg > 8)
      int cnt = min(e1 - j, 8);
      float2 av[8]; unsigned h[8];
      round_load(adj, at, 4, 0, j, cnt, hs1, c0, av, h);
      round_acc(cnt, adl1, hi, av, h, n10, n11, den1, mm1);
    }
    for (int j = b2 + 8; j < e2; j += 8){
      int cnt = min(e2 - j, 8);
      float2 av[8]; unsigned h[8];
      round_load(adj, aw, 8, 2, j, cnt, hs2, c0, av, h);
      round_acc(cnt, adl2, hi, av, h, n20, n21, den2, mm2);
    }
    float i1v = 1.f / (den1 + 1e-16f), i2v = 1.f / (den2 + 1e-16f);
    o0 = n10 * i1v + n20 * i2v + ldf(bsrc, 128 + c0, fm)     + ldf(bsrc, 256 + c0, fm);
    o1 = n11 * i1v + n21 * i2v + ldf(bsrc, 128 + c0 + 1, fm) + ldf(bsrc, 256 + c0 + 1, fm);
  }
  o0 = o0 > 0.f ? o0 : __expf(o0) - 1.f;   // ELU (2-ulp exp fine under bf16 rounding)
  o1 = o1 > 0.f ? o1 : __expf(o1) - 1.f;
  if (!FINAL){
    ushort_t* out = is_tok ? xt_out : xw_out;
    unsigned pack = (unsigned)f2b(o0) | ((unsigned)f2b(o1) << 16);
    *(unsigned*)(out + (long)d * 128 + c0) = pack;
  } else {
    const void* W = is_tok ? clsWt : clsWw;
    const void* b = is_tok ? clsbt : clsbw;
    float w00 = ldf(W, 4 * lane + 0, fm), w01 = ldf(W, 4 * lane + 1, fm);
    float w10 = ldf(W, 4 * lane + 2, fm), w11 = ldf(W, 4 * lane + 3, fm);
    float p0 = o0 * w00 + o1 * w10;
    float p1 = o0 * w01 + o1 * w11;
#pragma unroll
    for (int off = 32; off > 0; off >>= 1){ p0 += __shfl_xor(p0, off, 64); p1 += __shfl_xor(p1, off, 64); }
    if (lane == 0){
      long g = is_tok ? (long)NW + d : (long)d;
      float r0 = p0 + ldf(b, 0, fm);
      float r1 = p1 + ldf(b, 1, fm);
      if (fm){ ((float*)dout)[g * 2] = r0; ((float*)dout)[g * 2 + 1] = r1; }
      else { ((ushort_t*)dout)[g * 2] = f2b(r0); ((ushort_t*)dout)[g * 2 + 1] = f2b(r1); }
    }
  }
}

extern "C" void kernel_launch(void* const* d_in, const int* in_sizes, int n_in,
                              void* d_out, int out_size, void* d_ws, size_t ws_size,
                              hipStream_t stream){
  const void* x_wallet = d_in[0];
  const void* x_token  = d_in[1];
  const void* lin_w_W  = d_in[2];
  const void* lin_w_b  = d_in[3];
  const void* lin_t_W  = d_in[4];
  const void* lin_t_b  = d_in[5];
  const void* Wsrc0    = d_in[6];
  const void* Wdst0    = d_in[7];
  const void* atts0    = d_in[8];
  const void* attd0    = d_in[9];
  const void* b0       = d_in[10];
  const void* Wsrc1    = d_in[11];
  const void* Wdst1    = d_in[12];
  const void* atts1    = d_in[13];
  const void* attd1    = d_in[14];
  const void* b1       = d_in[15];
  const void* cls_w_W  = d_in[16];
  const void* cls_w_b  = d_in[17];
  const void* cls_t_W  = d_in[18];
  const void* cls_t_b  = d_in[19];
  const int* e_wt = (const int*)d_in[20];
  const int* e_tw = (const int*)d_in[21];
  const int* e_ww = (const int*)d_in[22];

  char* ws = (char*)d_ws;
  size_t off = 0;
  auto alloc = [&](size_t bytes) -> char* {
    char* p = ws + off; off += (bytes + 255) & ~(size_t)255; return p;
  };
  int* rowptr = (int*)alloc((size_t)(NSEG + 1) * 4);
  int* deg    = (int*)alloc((size_t)(NSEG + 1) * 4);   // doubles as fill cursor after scan
  int* adj    = (int*)alloc((size_t)3 * EE * 4);
  int* sums   = (int*)alloc(512 * 4);
  int* mode   = (int*)alloc(8);
  ushort_t* BtLw = (ushort_t*)alloc(64 * 128 * 2);
  ushort_t* BtLt = (ushort_t*)alloc(64 * 64 * 2);
  ushort_t* BtS0 = (ushort_t*)alloc(3 * 128 * 64 * 2);
  ushort_t* BtS1 = (ushort_t*)alloc(3 * 128 * 128 * 2);
  float* Uw0 = (float*)alloc(64 * 8 * 4);
  float* Ut0 = (float*)alloc(64 * 4 * 4);
  float* Uw1 = (float*)alloc(128 * 8 * 4);
  float* Ut1 = (float*)alloc(128 * 4 * 4);
  float* aw = (float*)alloc((size_t)NW * 8 * 4);
  float* at = (float*)alloc((size_t)NT * 4 * 4);
  ushort_t* hs0 = (ushort_t*)alloc((size_t)NW * 128 * 2);
  ushort_t* hs1 = (ushort_t*)alloc((size_t)NT * 128 * 2);
  ushort_t* hs2 = (ushort_t*)alloc((size_t)NW * 128 * 2);
  ushort_t* xbuf = (ushort_t*)alloc(((size_t)NW + NT) * 128 * 2);
  ushort_t* xw0 = xbuf;
  ushort_t* xt0 = xbuf + (size_t)NW * 64;
  ushort_t* xwB = xbuf;                         // aliases xw0+xt0 (both dead by then)
  ushort_t* xtB = xbuf + (size_t)NW * 128;      // disjoint from xw0/xt0
  (void)in_sizes; (void)n_in;

  if (off > ws_size){
    hipMemsetAsync(d_out, 0, (size_t)out_size * 2, stream);
    return;
  }

  hipMemsetAsync(deg, 0, (size_t)NSEG * 4, stream);
  detect_kern<<<1, 64, 0, stream>>>(e_wt, e_tw, e_ww, (const unsigned*)x_wallet, mode);

  TDesc8 td;
  td.d[0] = { lin_w_W, BtLw, 0, 128, 64 };
  td.d[1] = { lin_t_W, BtLt, 0, 64, 64 };
  for (int t = 0; t < 3; ++t){
    td.d[2 + t] = { Wsrc0, BtS0 + t * 128 * 64,  (long)t * 64 * 128,  64,  128 };
    td.d[5 + t] = { Wsrc1, BtS1 + t * 128 * 128, (long)t * 128 * 128, 128, 128 };
  }
  transpose8<<<512, 256, 0, stream>>>(td, mode);
  uprep<<<9, 256, 0, stream>>>(Wsrc0, Wdst0, atts0, attd0, Wsrc1, Wdst1, atts1, attd1, Uw0, Ut0, Uw1, Ut1, mode);

  int egrid = (3 * EE + 255) / 256;
  hist_kern<<<egrid, 256, 0, stream>>>(e_wt, e_tw, e_ww, mode, deg);
  int nch = (NSEG + 1023) / 1024;
  scan1<<<nch, 512, 0, stream>>>(deg, rowptr, sums);
  scan2<<<1, 512, 0, stream>>>(sums, nch);
  scan3<<<(NSEG + 255) / 256, 256, 0, stream>>>(rowptr, deg, sums);   // deg becomes cursor
  fill_kern<<<egrid, 256, 0, stream>>>(e_wt, e_tw, e_ww, mode, deg, adj);

  const int G = 512;
  int ncW = (NW + 127) / 128, ncT = (NT + 127) / 128;
  int agrid = NT / 4 + NW / 4;

  // input projections (external A, dtype per mode[1])
  gemm_kern<128, 64, true, true><<<G, 256, 0, stream>>>(x_wallet, BtLw, lin_w_b, xw0, NW, mode, ncW);
  gemm_kern<64, 64, true, true><<<G, 256, 0, stream>>>(x_token, BtLt, lin_t_b, xt0, NT, mode, ncT);

  // ---- layer 0 (K=64) ----
  a_kern<64, 8><<<(NW + 255) / 256, 256, 0, stream>>>(xw0, Uw0, aw, NW);
  a_kern<64, 4><<<(NT + 255) / 256, 256, 0, stream>>>(xt0, Ut0, at, NT);
  gemm_kern<64, 128, false, false><<<G, 256, 0, stream>>>(xw0, BtS0, nullptr, hs0, NW, mode, ncW);
  gemm_kern<64, 128, false, false><<<G, 256, 0, stream>>>(xt0, BtS0 + 128 * 64, nullptr, hs1, NT, mode, ncT);
  gemm_kern<64, 128, false, false><<<G, 256, 0, stream>>>(xw0, BtS0 + 2 * 128 * 64, nullptr, hs2, NW, mode, ncW);
  agg_all<false><<<agrid, 256, 0, stream>>>(rowptr, adj, aw, at, hs0, hs1, hs2, b0, xtB, xwB,
                                            nullptr, nullptr, nullptr, nullptr, nullptr, mode);

  // ---- layer 1 (K=128), classifier fused ----
  a_kern<128, 8><<<(NW + 255) / 256, 256, 0, stream>>>(xwB, Uw1, aw, NW);
  a_kern<128, 4><<<(NT + 255) / 256, 256, 0, stream>>>(xtB, Ut1, at, NT);
  gemm_kern<128, 128, false, false><<<G, 256, 0, stream>>>(xwB, BtS1, nullptr, hs0, NW, mode, ncW);
  gemm_kern<128, 128, false, false><<<G, 256, 0, stream>>>(xtB, BtS1 + 128 * 128, nullptr, hs1, NT, mode, ncT);
  gemm_kern<128, 128, false, false><<<G, 256, 0, stream>>>(xwB, BtS1 + 2 * 128 * 128, nullptr, hs2, NW, mode, ncW);
  agg_all<true><<<agrid, 256, 0, stream>>>(rowptr, adj, aw, at, hs0, hs1, hs2, b1, nullptr, nullptr,
                                           cls_w_W, cls_w_b, cls_t_W, cls_t_b, d_out, mode);
}